// Round 1
// 969.488 us; speedup vs baseline: 1.0578x; 1.0578x over previous
//
#include <hip/hip_runtime.h>

// RationalQuadratic: 4-layer MLP conditioner (bf16 MFMA GEMMs) + RQ spline.
// R9: fuse the RQ spline into the last GEMM's epilogue. gemm4 previously
// wrote P (201 MB bf16) and spline_kernel re-read it all — ~400 MB of HBM
// round-trip for ~11 us of VALU math. The fused kernel uses 128x96 tiles
// (96 = 4 dims x 24 padded params, so dim groups never span blocks),
// stages the fp32 output tile in LDS (stride 97: odd => <=2-way conflict
// reads), runs the spline per (row,dim), writes z directly and atomicAdds
// per-row ld partials. P is gone from the workspace (5120 -> 4096 B/row).
// Evidence: gemm4 at 135 us = 1.53 PF effective (61% dense peak; MfmaUtil
// 33% is the gfx94x-formula 2x undercount) — near its structural ceiling,
// so the win is removing the consumer round-trip, not rescheduling MFMA.

typedef __bf16 bf16_t;
typedef __bf16 bf16x8 __attribute__((ext_vector_type(8)));
typedef float f32x4 __attribute__((ext_vector_type(4)));

#define GLOAD_LDS16(g, l)                                               \
  __builtin_amdgcn_global_load_lds(                                     \
      (const __attribute__((address_space(1))) void*)(g),               \
      (__attribute__((address_space(3))) void*)(l), 16, 0, 0)

// ---------------------------------------------------------------------------
// W (K,N) fp32 row-major -> Wt (Npad,K) bf16 row-major. grid (K/64, Npad/64).
__global__ __launch_bounds__(256) void transpose_w(
    const float* __restrict__ W, bf16_t* __restrict__ Wt,
    int K, int N, int Npad) {
  __shared__ float tile[64][65];
  const int kt = blockIdx.x * 64;
  const int nt = blockIdx.y * 64;
  const int r4 = threadIdx.x >> 6;
  const int c = threadIdx.x & 63;
#pragma unroll
  for (int i = 0; i < 16; i++) {
    int r = i * 4 + r4;
    int gn = nt + c;
    tile[r][c] = (gn < N) ? W[(size_t)(kt + r) * N + gn] : 0.0f;
  }
  __syncthreads();
#pragma unroll
  for (int i = 0; i < 16; i++) {
    int r = i * 4 + r4;
    Wt[(size_t)(nt + r) * K + kt + c] = (bf16_t)tile[c][r];
  }
}

// W3 (1024,1472) -> Wt3p (1536,1024) bf16, cols regrouped per-dim with pad:
// padded col n' = d*24 + p (p<23 real, p==23 zero). grid (16, 24).
__global__ __launch_bounds__(256) void transpose_w3p(
    const float* __restrict__ W3, bf16_t* __restrict__ Wt) {
  __shared__ float tile[64][65];
  const int kt = blockIdx.x * 64;
  const int nt = blockIdx.y * 64;
  const int r4 = threadIdx.x >> 6;
  const int c = threadIdx.x & 63;
  const int np = nt + c;
  const int d = np / 24, p = np % 24;
#pragma unroll
  for (int i = 0; i < 16; i++) {
    int r = i * 4 + r4;
    tile[r][c] = (p < 23) ? W3[(size_t)(kt + r) * 1472 + d * 23 + p] : 0.0f;
  }
  __syncthreads();
#pragma unroll
  for (int i = 0; i < 16; i++) {
    int r = i * 4 + r4;
    Wt[(size_t)(nt + r) * 1024 + kt + c] = (bf16_t)tile[c][r];
  }
}

// b3 -> 24-stride padded copy. grid (6,256).
__global__ __launch_bounds__(256) void prep_b3(const float* __restrict__ b3,
                                               float* __restrict__ b3p) {
  int t = blockIdx.x * 256 + threadIdx.x;
  if (t < 1536) {
    int d = t / 24, p = t % 24;
    b3p[t] = (p < 23) ? b3[d * 23 + p] : 0.0f;
  }
}

// ---------------------------------------------------------------------------
// Also zeroes ld_out for this chunk (fused gemm accumulates into it).
__global__ __launch_bounds__(256) void build_x(
    const float* __restrict__ x1, const float* __restrict__ mask1,
    const float* __restrict__ ctx, bf16_t* __restrict__ X,
    float* __restrict__ ld_out, int boff) {
  int idx = blockIdx.x * 256 + threadIdx.x;
  int bl = idx >> 8;
  int c = idx & 255;
  size_t b = (size_t)(boff + bl);
  float v;
  if (c < 64)       v = x1[b * 64 + c];
  else if (c < 128) v = mask1[b * 64 + (c - 64)];
  else              v = ctx[b * 128 + (c - 128)];
  X[(size_t)bl * 256 + c] = (bf16_t)v;
  if (c == 0) ld_out[b] = 0.0f;
}

// ---------------------------------------------------------------------------
// GEMM body: 128x128 tile, 4 waves 2x2, 4x4 frags of 16x16x32 MFMA.
// Two BK=32 K-tiles per barrier pair (R4). Bank-swizzled LDS layout (R7):
// LDS (row, quad) holds global k-chunk (quad ^ ((row>>1)&3)) — conflicts = 0.
template <int RELU>
__device__ __forceinline__ void gemm_body(
    const bf16_t* __restrict__ A, const bf16_t* __restrict__ Bt,
    const float* __restrict__ bias, bf16_t* __restrict__ Cout, int N, int K) {
  __shared__ __align__(16) bf16_t As[2][128 * 32];
  __shared__ __align__(16) bf16_t Bs[2][128 * 32];
  const int tid = threadIdx.x;
  const int w = tid >> 6;
  const int lane = tid & 63;
  const int m0 = blockIdx.y * 128;
  const int n0 = blockIdx.x * 128;
  const int wm = (w & 1) * 64;
  const int wn = (w >> 1) * 64;
  const int lrow = lane & 15;
  const int quad = lane >> 4;

  f32x4 acc[4][4];
#pragma unroll
  for (int i = 0; i < 4; i++)
#pragma unroll
    for (int j = 0; j < 4; j++) acc[i][j] = (f32x4){0.f, 0.f, 0.f, 0.f};

  const int nPair = K >> 6;
  for (int kp = 0; kp < nPair; kp++) {
#pragma unroll
    for (int h = 0; h < 2; h++) {
      const int k0 = (kp << 6) + (h << 5);
#pragma unroll
      for (int c = 0; c < 2; c++) {
        const int chunk = w * 2 + c;
        const int byteoff = (chunk << 10) + lane * 16;
        const int row = byteoff >> 6;
        const int q = (byteoff >> 4) & 3;
        const int qs = q ^ ((row >> 1) & 3);  // swizzled global k-chunk
        const int kel = qs * 8;
        GLOAD_LDS16(A + (size_t)(m0 + row) * K + (k0 + kel),
                    As[h] + chunk * 512);
        GLOAD_LDS16(Bt + (size_t)(n0 + row) * K + (k0 + kel),
                    Bs[h] + chunk * 512);
      }
    }
    __syncthreads();
#pragma unroll
    for (int h = 0; h < 2; h++) {
      bf16x8 af[4], bfr[4];
#pragma unroll
      for (int i = 0; i < 4; i++) {
        const int row = wm + i * 16 + lrow;
        const int qs = quad ^ ((row >> 1) & 3);
        af[i] = *(const bf16x8*)(As[h] + row * 32 + qs * 8);
      }
#pragma unroll
      for (int j = 0; j < 4; j++) {
        const int row = wn + j * 16 + lrow;
        const int qs = quad ^ ((row >> 1) & 3);
        bfr[j] = *(const bf16x8*)(Bs[h] + row * 32 + qs * 8);
      }
#pragma unroll
      for (int i = 0; i < 4; i++)
#pragma unroll
        for (int j = 0; j < 4; j++)
          acc[i][j] = __builtin_amdgcn_mfma_f32_16x16x32_bf16(
              af[i], bfr[j], acc[i][j], 0, 0, 0);
    }
    __syncthreads();
  }

  // C/D layout (m89/m91): col = lane&15, row = quad*4 + reg.
  float bv[4];
#pragma unroll
  for (int j = 0; j < 4; j++) bv[j] = bias[n0 + wn + j * 16 + lrow];
#pragma unroll
  for (int i = 0; i < 4; i++) {
    int rbase = m0 + wm + i * 16 + quad * 4;
#pragma unroll
    for (int j = 0; j < 4; j++) {
      int col = n0 + wn + j * 16 + lrow;
#pragma unroll
      for (int r = 0; r < 4; r++) {
        float v = acc[i][j][r] + bv[j];
        if (RELU) v = fmaxf(v, 0.0f);
        Cout[(size_t)(rbase + r) * N + col] = (bf16_t)v;
      }
    }
  }
}

__global__ __launch_bounds__(256) void gemm_bt(
    const bf16_t* __restrict__ A, const bf16_t* __restrict__ Bt,
    const float* __restrict__ bias, bf16_t* __restrict__ Cout, int N, int K) {
  gemm_body<1>(A, Bt, bias, Cout, N, K);
}

// ---------------------------------------------------------------------------
// Fused last GEMM + RQ spline. Tile 128 rows x 96 cols (= 4 dims x 24
// padded params). 4 waves, each 64x48 (4x3 frags). Same dual-K barrier
// pair + bank-swizzle staging as gemm_body. Epilogue: fp32 P-tile into LDS
// (stride 97 => reads <=2-way conflict = free), then 512 (row,dim) splines
// across 256 threads; z written directly, ld via 4-lane shfl + atomicAdd.
__global__ __launch_bounds__(256) void gemm_rq_fused(
    const bf16_t* __restrict__ A, const bf16_t* __restrict__ Bt,
    const float* __restrict__ b3p, const float* __restrict__ x2,
    float* __restrict__ z_out, float* __restrict__ ld_out,
    int boff, int K) {
  union alignas(16) SM {
    struct { bf16_t As[2][128 * 32]; bf16_t Bs[2][96 * 32]; } s;  // 28672 B
    float Pt[128 * 97];                                           // 49664 B
  };
  __shared__ SM sm;
  const int tid = threadIdx.x;
  const int w = tid >> 6;
  const int lane = tid & 63;
  const int m0 = blockIdx.y * 128;
  const int n0 = blockIdx.x * 96;
  const int wm = (w & 1) * 64;
  const int wn = (w >> 1) * 48;
  const int lrow = lane & 15;
  const int quad = lane >> 4;

  f32x4 acc[4][3];
#pragma unroll
  for (int i = 0; i < 4; i++)
#pragma unroll
    for (int j = 0; j < 3; j++) acc[i][j] = (f32x4){0.f, 0.f, 0.f, 0.f};

  const int nPair = K >> 6;
  for (int kp = 0; kp < nPair; kp++) {
#pragma unroll
    for (int h = 0; h < 2; h++) {
      const int k0 = (kp << 6) + (h << 5);
      // 14 chunks per half (A: 8, B: 6), round-robin across 4 waves.
#pragma unroll
      for (int c = 0; c < 4; c++) {
        const int chunk = c * 4 + w;
        if (chunk < 8) {
          const int byteoff = (chunk << 10) + lane * 16;
          const int row = byteoff >> 6;
          const int qs = ((byteoff >> 4) & 3) ^ ((row >> 1) & 3);
          GLOAD_LDS16(A + (size_t)(m0 + row) * K + (k0 + qs * 8),
                      sm.s.As[h] + chunk * 512);
        } else if (chunk < 14) {
          const int cb = chunk - 8;
          const int byteoff = (cb << 10) + lane * 16;
          const int row = byteoff >> 6;
          const int qs = ((byteoff >> 4) & 3) ^ ((row >> 1) & 3);
          GLOAD_LDS16(Bt + (size_t)(n0 + row) * K + (k0 + qs * 8),
                      sm.s.Bs[h] + cb * 512);
        }
      }
    }
    __syncthreads();
#pragma unroll
    for (int h = 0; h < 2; h++) {
      bf16x8 af[4], bfr[3];
#pragma unroll
      for (int i = 0; i < 4; i++) {
        const int row = wm + i * 16 + lrow;
        const int qs = quad ^ ((row >> 1) & 3);
        af[i] = *(const bf16x8*)(sm.s.As[h] + row * 32 + qs * 8);
      }
#pragma unroll
      for (int j = 0; j < 3; j++) {
        const int row = wn + j * 16 + lrow;
        const int qs = quad ^ ((row >> 1) & 3);
        bfr[j] = *(const bf16x8*)(sm.s.Bs[h] + row * 32 + qs * 8);
      }
#pragma unroll
      for (int i = 0; i < 4; i++)
#pragma unroll
        for (int j = 0; j < 3; j++)
          acc[i][j] = __builtin_amdgcn_mfma_f32_16x16x32_bf16(
              af[i], bfr[j], acc[i][j], 0, 0, 0);
    }
    __syncthreads();
  }

  // --- P-tile (fp32, +bias) into LDS. Last barrier above guarantees no
  // wave still reads As/Bs. C/D layout: col = lane&15, row = quad*4 + reg.
  float bv[3];
#pragma unroll
  for (int j = 0; j < 3; j++) bv[j] = b3p[n0 + wn + j * 16 + lrow];
#pragma unroll
  for (int i = 0; i < 4; i++) {
    const int rbase = wm + i * 16 + quad * 4;
#pragma unroll
    for (int j = 0; j < 3; j++) {
      const int col = wn + j * 16 + lrow;
#pragma unroll
      for (int r = 0; r < 4; r++)
        sm.Pt[(rbase + r) * 97 + col] = acc[i][j][r] + bv[j];
    }
  }
  __syncthreads();

  // --- spline: thread t handles rows (t>>2) and (t>>2)+64, dim t&3.
  const float SHIFT = 0.54132485f;     // log(e-1)
  const float SHIFT_DX = 5.1944682f;   // log(exp(6.0-0.8)-1)
  const float left = -3.0f;
  const float delta_x = 0.8f + log1pf(expf(SHIFT_DX));
  const float right = left + delta_x;
  const float scale = delta_x;
  const int dloc = tid & 3;
  const int dg = blockIdx.x * 4 + dloc;

#pragma unroll
  for (int rr = 0; rr < 2; rr++) {
    const int row = (tid >> 2) + rr * 64;
    const float* pr = sm.Pt + row * 97 + dloc * 24;
    const size_t bg = (size_t)(boff + m0 + row);
    const float x = x2[bg * 64 + dg];

    float mw = pr[0];
#pragma unroll
    for (int j = 1; j < 8; j++) mw = fmaxf(mw, pr[j]);
    float ew[8], swv = 0.f;
#pragma unroll
    for (int j = 0; j < 8; j++) { ew[j] = expf(pr[j] - mw); swv += ew[j]; }
    float invw = 1.0f / swv;
    float cw[9];
    cw[0] = left;
    float cum = 0.f;
#pragma unroll
    for (int j = 0; j < 8; j++) {
      cum += 0.1f + 0.2f * ew[j] * invw;
      cw[j + 1] = left + scale * cum;
    }
    float mh = pr[8];
#pragma unroll
    for (int j = 9; j < 16; j++) mh = fmaxf(mh, pr[j]);
    float eh[8], shv = 0.f;
#pragma unroll
    for (int j = 0; j < 8; j++) { eh[j] = expf(pr[8 + j] - mh); shv += eh[j]; }
    float invh = 1.0f / shv;
    float chh[9];
    chh[0] = left;
    float cumh = 0.f;
#pragma unroll
    for (int j = 0; j < 8; j++) {
      cumh += 0.1f + 0.2f * eh[j] * invh;
      chh[j + 1] = left + scale * cumh;
    }
    float dv[9];
    dv[0] = 1.0f;
    dv[8] = 1.0f;
#pragma unroll
    for (int j = 0; j < 7; j++) {
      float v = pr[16 + j] + SHIFT;
      dv[j + 1] = 0.001f + ((v > 20.f) ? v : log1pf(expf(v)));
    }
    int cnt = 0;
#pragma unroll
    for (int j = 0; j < 8; j++) cnt += (cw[j] <= x) ? 1 : 0;
    cnt += ((cw[8] + 1e-6f) <= x) ? 1 : 0;
    int idx = cnt - 1;
    idx = idx < 0 ? 0 : (idx > 7 ? 7 : idx);
    float x_k = cw[0], x_k1 = cw[1], y_k = chh[0], y_k1 = chh[1];
    float d0v = dv[0], d1v = dv[1];
#pragma unroll
    for (int j = 1; j < 8; j++) {
      bool s = (idx == j);
      x_k = s ? cw[j] : x_k;
      x_k1 = s ? cw[j + 1] : x_k1;
      y_k = s ? chh[j] : y_k;
      y_k1 = s ? chh[j + 1] : y_k1;
      d0v = s ? dv[j] : d0v;
      d1v = s ? dv[j + 1] : d1v;
    }
    float x_kd = x_k1 - x_k;
    float y_kd = y_k1 - y_k;
    float s_k = y_kd / x_kd;
    float xi = (x - x_k) / x_kd;
    float xi1m = xi * (1.f - xi);
    float alpha_k = y_kd * (s_k * xi * xi + d0v * xi1m);
    float beta_k = s_k + (d1v + d0v - 2.f * s_k) * xi1m;
    float z_sp = y_k + alpha_k / fmaxf(beta_k, 1e-8f);
    float oxi = 1.f - xi;
    float num = s_k * s_k * (d1v * xi * xi + 2.f * s_k * xi1m + d0v * oxi * oxi);
    float ld_sp = logf(fmaxf(num, 1e-8f)) - 2.f * logf(fmaxf(beta_k, 1e-8f));

    bool inside = (left <= x) && (x < right);
    z_out[bg * 64 + dg] = inside ? z_sp : x;
    float ldv = inside ? ld_sp : 0.f;
    ldv += __shfl_xor(ldv, 1);
    ldv += __shfl_xor(ldv, 2);
    if (dloc == 0) atomicAdd(&ld_out[bg], ldv);
  }
}

// ---------------------------------------------------------------------------
extern "C" void kernel_launch(void* const* d_in, const int* in_sizes, int n_in,
                              void* d_out, int out_size, void* d_ws,
                              size_t ws_size, hipStream_t stream) {
  const float* x1 = (const float*)d_in[0];
  const float* x2 = (const float*)d_in[1];
  const float* ctx = (const float*)d_in[2];
  const float* mask1 = (const float*)d_in[3];
  const float* W0 = (const float*)d_in[4];
  const float* b0 = (const float*)d_in[5];
  const float* W1 = (const float*)d_in[6];
  const float* b1 = (const float*)d_in[7];
  const float* W2 = (const float*)d_in[8];
  const float* b2 = (const float*)d_in[9];
  const float* W3 = (const float*)d_in[10];
  const float* b3 = (const float*)d_in[11];
  float* out = (float*)d_out;

  const int B = 65536;
  char* ws = (char*)d_ws;

  bf16_t* Wt0 = (bf16_t*)ws;                           // 1024x256  (512 KB)
  bf16_t* Wt1 = (bf16_t*)(ws + 524288);                // 1024x1024 (2 MB)
  bf16_t* Wt2 = (bf16_t*)(ws + 524288 + 2097152);      // 1024x1024 (2 MB)
  bf16_t* Wt3 = (bf16_t*)(ws + 524288 + 2 * 2097152);  // 1536x1024 (3 MB)
  float* b3p = (float*)(ws + 524288 + 2 * 2097152 + 3145728);  // 6 KB
  const size_t wend = 524288 + 2 * 2097152 + 3145728 + 8192;

  // Adaptive chunking, prefer C=1. Per-row: HA 2048 B + aliased region
  // 2048 B (X 512 / HB 2048 — lifetimes disjoint; P eliminated by fusion).
  int C = 4;
  if (wend + (size_t)B * 4096 <= ws_size) C = 1;
  else if (wend + (size_t)(B / 2) * 4096 <= ws_size) C = 2;
  const int Bc = B / C;
  bf16_t* HA = (bf16_t*)(ws + wend);
  char* R = ws + wend + (size_t)Bc * 2048;
  bf16_t* X = (bf16_t*)R;
  bf16_t* HB = (bf16_t*)R;
  float* ld_out = out + (size_t)B * 64;

  transpose_w<<<dim3(4, 16), 256, 0, stream>>>(W0, Wt0, 256, 1024, 1024);
  transpose_w<<<dim3(16, 16), 256, 0, stream>>>(W1, Wt1, 1024, 1024, 1024);
  transpose_w<<<dim3(16, 16), 256, 0, stream>>>(W2, Wt2, 1024, 1024, 1024);
  transpose_w3p<<<dim3(16, 24), 256, 0, stream>>>(W3, Wt3);
  prep_b3<<<6, 256, 0, stream>>>(b3, b3p);

  for (int c = 0; c < C; c++) {
    const int boff = c * Bc;
    build_x<<<Bc, 256, 0, stream>>>(x1, mask1, ctx, X, ld_out, boff);
    gemm_bt<<<dim3(8, Bc / 128), 256, 0, stream>>>(X, Wt0, b0, HA, 1024, 256);
    gemm_bt<<<dim3(8, Bc / 128), 256, 0, stream>>>(HA, Wt1, b1, HB, 1024, 1024);
    gemm_bt<<<dim3(8, Bc / 128), 256, 0, stream>>>(HB, Wt2, b2, HA, 1024, 1024);
    gemm_rq_fused<<<dim3(16, Bc / 128), 256, 0, stream>>>(
        HA, Wt3, b3p, x2, out, ld_out, boff, 1024);
  }
}

// Round 2
// 944.411 us; speedup vs baseline: 1.0858x; 1.0266x over previous
//
#include <hip/hip_runtime.h>

// RationalQuadratic: 4-layer MLP conditioner (bf16 MFMA GEMMs) + RQ spline.
// R10: R9 (spline fused into last GEMM) with the P-tile staged in LDS as
// bf16 instead of fp32. Evidence: R9's fused kernel ran 195us vs gemm4's
// 135us with LDS_Block_Size=49664 (fp32 Pt union) capping residency at 3
// blocks/CU (Occupancy 32%, MfmaUtil 23%) — this schedule hides HBM latency
// purely via co-resident blocks, so occupancy is the lever. bf16 Pt
// (stride 104: 16B-aligned fragments, conflict-free b128 reads) shrinks the
// union to 28672B -> 5 blocks/CU. bf16 P is accuracy-proven: R8 stored P
// globally as bf16 with identical absmax (0.03125).

typedef __bf16 bf16_t;
typedef __bf16 bf16x8 __attribute__((ext_vector_type(8)));
typedef float f32x4 __attribute__((ext_vector_type(4)));

#define GLOAD_LDS16(g, l)                                               \
  __builtin_amdgcn_global_load_lds(                                     \
      (const __attribute__((address_space(1))) void*)(g),               \
      (__attribute__((address_space(3))) void*)(l), 16, 0, 0)

// ---------------------------------------------------------------------------
// W (K,N) fp32 row-major -> Wt (Npad,K) bf16 row-major. grid (K/64, Npad/64).
__global__ __launch_bounds__(256) void transpose_w(
    const float* __restrict__ W, bf16_t* __restrict__ Wt,
    int K, int N, int Npad) {
  __shared__ float tile[64][65];
  const int kt = blockIdx.x * 64;
  const int nt = blockIdx.y * 64;
  const int r4 = threadIdx.x >> 6;
  const int c = threadIdx.x & 63;
#pragma unroll
  for (int i = 0; i < 16; i++) {
    int r = i * 4 + r4;
    int gn = nt + c;
    tile[r][c] = (gn < N) ? W[(size_t)(kt + r) * N + gn] : 0.0f;
  }
  __syncthreads();
#pragma unroll
  for (int i = 0; i < 16; i++) {
    int r = i * 4 + r4;
    Wt[(size_t)(nt + r) * K + kt + c] = (bf16_t)tile[c][r];
  }
}

// W3 (1024,1472) -> Wt3p (1536,1024) bf16, cols regrouped per-dim with pad:
// padded col n' = d*24 + p (p<23 real, p==23 zero). grid (16, 24).
__global__ __launch_bounds__(256) void transpose_w3p(
    const float* __restrict__ W3, bf16_t* __restrict__ Wt) {
  __shared__ float tile[64][65];
  const int kt = blockIdx.x * 64;
  const int nt = blockIdx.y * 64;
  const int r4 = threadIdx.x >> 6;
  const int c = threadIdx.x & 63;
  const int np = nt + c;
  const int d = np / 24, p = np % 24;
#pragma unroll
  for (int i = 0; i < 16; i++) {
    int r = i * 4 + r4;
    tile[r][c] = (p < 23) ? W3[(size_t)(kt + r) * 1472 + d * 23 + p] : 0.0f;
  }
  __syncthreads();
#pragma unroll
  for (int i = 0; i < 16; i++) {
    int r = i * 4 + r4;
    Wt[(size_t)(nt + r) * 1024 + kt + c] = (bf16_t)tile[c][r];
  }
}

// b3 -> 24-stride padded copy. grid (6,256).
__global__ __launch_bounds__(256) void prep_b3(const float* __restrict__ b3,
                                               float* __restrict__ b3p) {
  int t = blockIdx.x * 256 + threadIdx.x;
  if (t < 1536) {
    int d = t / 24, p = t % 24;
    b3p[t] = (p < 23) ? b3[d * 23 + p] : 0.0f;
  }
}

// ---------------------------------------------------------------------------
// Also zeroes ld_out for this chunk (fused gemm accumulates into it).
__global__ __launch_bounds__(256) void build_x(
    const float* __restrict__ x1, const float* __restrict__ mask1,
    const float* __restrict__ ctx, bf16_t* __restrict__ X,
    float* __restrict__ ld_out, int boff) {
  int idx = blockIdx.x * 256 + threadIdx.x;
  int bl = idx >> 8;
  int c = idx & 255;
  size_t b = (size_t)(boff + bl);
  float v;
  if (c < 64)       v = x1[b * 64 + c];
  else if (c < 128) v = mask1[b * 64 + (c - 64)];
  else              v = ctx[b * 128 + (c - 128)];
  X[(size_t)bl * 256 + c] = (bf16_t)v;
  if (c == 0) ld_out[b] = 0.0f;
}

// ---------------------------------------------------------------------------
// GEMM body: 128x128 tile, 4 waves 2x2, 4x4 frags of 16x16x32 MFMA.
// Two BK=32 K-tiles per barrier pair (R4). Bank-swizzled LDS layout (R7):
// LDS (row, quad) holds global k-chunk (quad ^ ((row>>1)&3)) — conflicts = 0.
template <int RELU>
__device__ __forceinline__ void gemm_body(
    const bf16_t* __restrict__ A, const bf16_t* __restrict__ Bt,
    const float* __restrict__ bias, bf16_t* __restrict__ Cout, int N, int K) {
  __shared__ __align__(16) bf16_t As[2][128 * 32];
  __shared__ __align__(16) bf16_t Bs[2][128 * 32];
  const int tid = threadIdx.x;
  const int w = tid >> 6;
  const int lane = tid & 63;
  const int m0 = blockIdx.y * 128;
  const int n0 = blockIdx.x * 128;
  const int wm = (w & 1) * 64;
  const int wn = (w >> 1) * 64;
  const int lrow = lane & 15;
  const int quad = lane >> 4;

  f32x4 acc[4][4];
#pragma unroll
  for (int i = 0; i < 4; i++)
#pragma unroll
    for (int j = 0; j < 4; j++) acc[i][j] = (f32x4){0.f, 0.f, 0.f, 0.f};

  const int nPair = K >> 6;
  for (int kp = 0; kp < nPair; kp++) {
#pragma unroll
    for (int h = 0; h < 2; h++) {
      const int k0 = (kp << 6) + (h << 5);
#pragma unroll
      for (int c = 0; c < 2; c++) {
        const int chunk = w * 2 + c;
        const int byteoff = (chunk << 10) + lane * 16;
        const int row = byteoff >> 6;
        const int q = (byteoff >> 4) & 3;
        const int qs = q ^ ((row >> 1) & 3);  // swizzled global k-chunk
        const int kel = qs * 8;
        GLOAD_LDS16(A + (size_t)(m0 + row) * K + (k0 + kel),
                    As[h] + chunk * 512);
        GLOAD_LDS16(Bt + (size_t)(n0 + row) * K + (k0 + kel),
                    Bs[h] + chunk * 512);
      }
    }
    __syncthreads();
#pragma unroll
    for (int h = 0; h < 2; h++) {
      bf16x8 af[4], bfr[4];
#pragma unroll
      for (int i = 0; i < 4; i++) {
        const int row = wm + i * 16 + lrow;
        const int qs = quad ^ ((row >> 1) & 3);
        af[i] = *(const bf16x8*)(As[h] + row * 32 + qs * 8);
      }
#pragma unroll
      for (int j = 0; j < 4; j++) {
        const int row = wn + j * 16 + lrow;
        const int qs = quad ^ ((row >> 1) & 3);
        bfr[j] = *(const bf16x8*)(Bs[h] + row * 32 + qs * 8);
      }
#pragma unroll
      for (int i = 0; i < 4; i++)
#pragma unroll
        for (int j = 0; j < 4; j++)
          acc[i][j] = __builtin_amdgcn_mfma_f32_16x16x32_bf16(
              af[i], bfr[j], acc[i][j], 0, 0, 0);
    }
    __syncthreads();
  }

  // C/D layout (m89/m91): col = lane&15, row = quad*4 + reg.
  float bv[4];
#pragma unroll
  for (int j = 0; j < 4; j++) bv[j] = bias[n0 + wn + j * 16 + lrow];
#pragma unroll
  for (int i = 0; i < 4; i++) {
    int rbase = m0 + wm + i * 16 + quad * 4;
#pragma unroll
    for (int j = 0; j < 4; j++) {
      int col = n0 + wn + j * 16 + lrow;
#pragma unroll
      for (int r = 0; r < 4; r++) {
        float v = acc[i][j][r] + bv[j];
        if (RELU) v = fmaxf(v, 0.0f);
        Cout[(size_t)(rbase + r) * N + col] = (bf16_t)v;
      }
    }
  }
}

__global__ __launch_bounds__(256) void gemm_bt(
    const bf16_t* __restrict__ A, const bf16_t* __restrict__ Bt,
    const float* __restrict__ bias, bf16_t* __restrict__ Cout, int N, int K) {
  gemm_body<1>(A, Bt, bias, Cout, N, K);
}

// ---------------------------------------------------------------------------
// Fused last GEMM + RQ spline. Tile 128 rows x 96 cols (= 4 dims x 24
// padded params). 4 waves, each 64x48 (4x3 frags). Same dual-K barrier
// pair + bank-swizzle staging as gemm_body. Epilogue: bf16 P-tile into LDS
// (stride 104 bf16: every 24-aligned fragment is 16B-aligned; b128 reads
// hit all 8 bank-groups evenly = conflict-free minimum). Union keeps LDS
// at 28672B -> 5 blocks/CU (R9's fp32 Pt was 49664B -> 3 blocks, the
// occupancy cap behind MfmaUtil 23%). Spline: z written directly, ld via
// 4-lane shfl + atomicAdd.
__global__ __launch_bounds__(256) void gemm_rq_fused(
    const bf16_t* __restrict__ A, const bf16_t* __restrict__ Bt,
    const float* __restrict__ b3p, const float* __restrict__ x2,
    float* __restrict__ z_out, float* __restrict__ ld_out,
    int boff, int K) {
  union alignas(16) SM {
    struct { bf16_t As[2][128 * 32]; bf16_t Bs[2][96 * 32]; } s;  // 28672 B
    bf16_t Pt[128 * 104];                                         // 26624 B
  };
  __shared__ SM sm;
  const int tid = threadIdx.x;
  const int w = tid >> 6;
  const int lane = tid & 63;
  const int m0 = blockIdx.y * 128;
  const int n0 = blockIdx.x * 96;
  const int wm = (w & 1) * 64;
  const int wn = (w >> 1) * 48;
  const int lrow = lane & 15;
  const int quad = lane >> 4;

  f32x4 acc[4][3];
#pragma unroll
  for (int i = 0; i < 4; i++)
#pragma unroll
    for (int j = 0; j < 3; j++) acc[i][j] = (f32x4){0.f, 0.f, 0.f, 0.f};

  const int nPair = K >> 6;
  for (int kp = 0; kp < nPair; kp++) {
#pragma unroll
    for (int h = 0; h < 2; h++) {
      const int k0 = (kp << 6) + (h << 5);
      // 14 chunks per half (A: 8, B: 6), round-robin across 4 waves.
#pragma unroll
      for (int c = 0; c < 4; c++) {
        const int chunk = c * 4 + w;
        if (chunk < 8) {
          const int byteoff = (chunk << 10) + lane * 16;
          const int row = byteoff >> 6;
          const int qs = ((byteoff >> 4) & 3) ^ ((row >> 1) & 3);
          GLOAD_LDS16(A + (size_t)(m0 + row) * K + (k0 + qs * 8),
                      sm.s.As[h] + chunk * 512);
        } else if (chunk < 14) {
          const int cb = chunk - 8;
          const int byteoff = (cb << 10) + lane * 16;
          const int row = byteoff >> 6;
          const int qs = ((byteoff >> 4) & 3) ^ ((row >> 1) & 3);
          GLOAD_LDS16(Bt + (size_t)(n0 + row) * K + (k0 + qs * 8),
                      sm.s.Bs[h] + cb * 512);
        }
      }
    }
    __syncthreads();
#pragma unroll
    for (int h = 0; h < 2; h++) {
      bf16x8 af[4], bfr[3];
#pragma unroll
      for (int i = 0; i < 4; i++) {
        const int row = wm + i * 16 + lrow;
        const int qs = quad ^ ((row >> 1) & 3);
        af[i] = *(const bf16x8*)(sm.s.As[h] + row * 32 + qs * 8);
      }
#pragma unroll
      for (int j = 0; j < 3; j++) {
        const int row = wn + j * 16 + lrow;
        const int qs = quad ^ ((row >> 1) & 3);
        bfr[j] = *(const bf16x8*)(sm.s.Bs[h] + row * 32 + qs * 8);
      }
#pragma unroll
      for (int i = 0; i < 4; i++)
#pragma unroll
        for (int j = 0; j < 3; j++)
          acc[i][j] = __builtin_amdgcn_mfma_f32_16x16x32_bf16(
              af[i], bfr[j], acc[i][j], 0, 0, 0);
    }
    __syncthreads();
  }

  // --- P-tile (bf16, +bias) into LDS. Last barrier above guarantees no
  // wave still reads As/Bs. C/D layout: col = lane&15, row = quad*4 + reg.
  // bf16 rounding of P is accuracy-proven (R8 stored P globally as bf16,
  // same absmax 0.03125).
  float bv[3];
#pragma unroll
  for (int j = 0; j < 3; j++) bv[j] = b3p[n0 + wn + j * 16 + lrow];
#pragma unroll
  for (int i = 0; i < 4; i++) {
    const int rbase = wm + i * 16 + quad * 4;
#pragma unroll
    for (int j = 0; j < 3; j++) {
      const int col = wn + j * 16 + lrow;
#pragma unroll
      for (int r = 0; r < 4; r++)
        sm.Pt[(rbase + r) * 104 + col] = (bf16_t)(acc[i][j][r] + bv[j]);
    }
  }
  __syncthreads();

  // --- spline: thread t handles rows (t>>2) and (t>>2)+64, dim t&3.
  const float SHIFT = 0.54132485f;     // log(e-1)
  const float SHIFT_DX = 5.1944682f;   // log(exp(6.0-0.8)-1)
  const float left = -3.0f;
  const float delta_x = 0.8f + log1pf(expf(SHIFT_DX));
  const float right = left + delta_x;
  const float scale = delta_x;
  const int dloc = tid & 3;
  const int dg = blockIdx.x * 4 + dloc;

#pragma unroll
  for (int rr = 0; rr < 2; rr++) {
    const int row = (tid >> 2) + rr * 64;
    const bf16_t* pr = sm.Pt + row * 104 + dloc * 24;
    const size_t bg = (size_t)(boff + m0 + row);
    const float x = x2[bg * 64 + dg];

    // 3x ds_read_b128 (16B-aligned: 104 and 24 are both multiples of 8
    // bf16), then statically-indexed register array (rule #20).
    bf16x8 v0 = *(const bf16x8*)(pr);
    bf16x8 v1 = *(const bf16x8*)(pr + 8);
    bf16x8 v2 = *(const bf16x8*)(pr + 16);
    float pv[24];
#pragma unroll
    for (int j = 0; j < 8; j++) pv[j] = (float)v0[j];
#pragma unroll
    for (int j = 0; j < 8; j++) pv[8 + j] = (float)v1[j];
#pragma unroll
    for (int j = 0; j < 8; j++) pv[16 + j] = (float)v2[j];

    float mw = pv[0];
#pragma unroll
    for (int j = 1; j < 8; j++) mw = fmaxf(mw, pv[j]);
    float ew[8], swv = 0.f;
#pragma unroll
    for (int j = 0; j < 8; j++) { ew[j] = expf(pv[j] - mw); swv += ew[j]; }
    float invw = 1.0f / swv;
    float cw[9];
    cw[0] = left;
    float cum = 0.f;
#pragma unroll
    for (int j = 0; j < 8; j++) {
      cum += 0.1f + 0.2f * ew[j] * invw;
      cw[j + 1] = left + scale * cum;
    }
    float mh = pv[8];
#pragma unroll
    for (int j = 9; j < 16; j++) mh = fmaxf(mh, pv[j]);
    float eh[8], shv = 0.f;
#pragma unroll
    for (int j = 0; j < 8; j++) { eh[j] = expf(pv[8 + j] - mh); shv += eh[j]; }
    float invh = 1.0f / shv;
    float chh[9];
    chh[0] = left;
    float cumh = 0.f;
#pragma unroll
    for (int j = 0; j < 8; j++) {
      cumh += 0.1f + 0.2f * eh[j] * invh;
      chh[j + 1] = left + scale * cumh;
    }
    float dv[9];
    dv[0] = 1.0f;
    dv[8] = 1.0f;
#pragma unroll
    for (int j = 0; j < 7; j++) {
      float v = pv[16 + j] + SHIFT;
      dv[j + 1] = 0.001f + ((v > 20.f) ? v : log1pf(expf(v)));
    }
    int cnt = 0;
#pragma unroll
    for (int j = 0; j < 8; j++) cnt += (cw[j] <= x) ? 1 : 0;
    cnt += ((cw[8] + 1e-6f) <= x) ? 1 : 0;
    int idx = cnt - 1;
    idx = idx < 0 ? 0 : (idx > 7 ? 7 : idx);
    float x_k = cw[0], x_k1 = cw[1], y_k = chh[0], y_k1 = chh[1];
    float d0v = dv[0], d1v = dv[1];
#pragma unroll
    for (int j = 1; j < 8; j++) {
      bool s = (idx == j);
      x_k = s ? cw[j] : x_k;
      x_k1 = s ? cw[j + 1] : x_k1;
      y_k = s ? chh[j] : y_k;
      y_k1 = s ? chh[j + 1] : y_k1;
      d0v = s ? dv[j] : d0v;
      d1v = s ? dv[j + 1] : d1v;
    }
    float x_kd = x_k1 - x_k;
    float y_kd = y_k1 - y_k;
    float s_k = y_kd / x_kd;
    float xi = (x - x_k) / x_kd;
    float xi1m = xi * (1.f - xi);
    float alpha_k = y_kd * (s_k * xi * xi + d0v * xi1m);
    float beta_k = s_k + (d1v + d0v - 2.f * s_k) * xi1m;
    float z_sp = y_k + alpha_k / fmaxf(beta_k, 1e-8f);
    float oxi = 1.f - xi;
    float num = s_k * s_k * (d1v * xi * xi + 2.f * s_k * xi1m + d0v * oxi * oxi);
    float ld_sp = logf(fmaxf(num, 1e-8f)) - 2.f * logf(fmaxf(beta_k, 1e-8f));

    bool inside = (left <= x) && (x < right);
    z_out[bg * 64 + dg] = inside ? z_sp : x;
    float ldv = inside ? ld_sp : 0.f;
    ldv += __shfl_xor(ldv, 1);
    ldv += __shfl_xor(ldv, 2);
    if (dloc == 0) atomicAdd(&ld_out[bg], ldv);
  }
}

// ---------------------------------------------------------------------------
extern "C" void kernel_launch(void* const* d_in, const int* in_sizes, int n_in,
                              void* d_out, int out_size, void* d_ws,
                              size_t ws_size, hipStream_t stream) {
  const float* x1 = (const float*)d_in[0];
  const float* x2 = (const float*)d_in[1];
  const float* ctx = (const float*)d_in[2];
  const float* mask1 = (const float*)d_in[3];
  const float* W0 = (const float*)d_in[4];
  const float* b0 = (const float*)d_in[5];
  const float* W1 = (const float*)d_in[6];
  const float* b1 = (const float*)d_in[7];
  const float* W2 = (const float*)d_in[8];
  const float* b2 = (const float*)d_in[9];
  const float* W3 = (const float*)d_in[10];
  const float* b3 = (const float*)d_in[11];
  float* out = (float*)d_out;

  const int B = 65536;
  char* ws = (char*)d_ws;

  bf16_t* Wt0 = (bf16_t*)ws;                           // 1024x256  (512 KB)
  bf16_t* Wt1 = (bf16_t*)(ws + 524288);                // 1024x1024 (2 MB)
  bf16_t* Wt2 = (bf16_t*)(ws + 524288 + 2097152);      // 1024x1024 (2 MB)
  bf16_t* Wt3 = (bf16_t*)(ws + 524288 + 2 * 2097152);  // 1536x1024 (3 MB)
  float* b3p = (float*)(ws + 524288 + 2 * 2097152 + 3145728);  // 6 KB
  const size_t wend = 524288 + 2 * 2097152 + 3145728 + 8192;

  // Adaptive chunking, prefer C=1. Per-row: HA 2048 B + aliased region
  // 2048 B (X 512 / HB 2048 — lifetimes disjoint; P eliminated by fusion).
  int C = 4;
  if (wend + (size_t)B * 4096 <= ws_size) C = 1;
  else if (wend + (size_t)(B / 2) * 4096 <= ws_size) C = 2;
  const int Bc = B / C;
  bf16_t* HA = (bf16_t*)(ws + wend);
  char* R = ws + wend + (size_t)Bc * 2048;
  bf16_t* X = (bf16_t*)R;
  bf16_t* HB = (bf16_t*)R;
  float* ld_out = out + (size_t)B * 64;

  transpose_w<<<dim3(4, 16), 256, 0, stream>>>(W0, Wt0, 256, 1024, 1024);
  transpose_w<<<dim3(16, 16), 256, 0, stream>>>(W1, Wt1, 1024, 1024, 1024);
  transpose_w<<<dim3(16, 16), 256, 0, stream>>>(W2, Wt2, 1024, 1024, 1024);
  transpose_w3p<<<dim3(16, 24), 256, 0, stream>>>(W3, Wt3);
  prep_b3<<<6, 256, 0, stream>>>(b3, b3p);

  for (int c = 0; c < C; c++) {
    const int boff = c * Bc;
    build_x<<<Bc, 256, 0, stream>>>(x1, mask1, ctx, X, ld_out, boff);
    gemm_bt<<<dim3(8, Bc / 128), 256, 0, stream>>>(X, Wt0, b0, HA, 1024, 256);
    gemm_bt<<<dim3(8, Bc / 128), 256, 0, stream>>>(HA, Wt1, b1, HB, 1024, 1024);
    gemm_bt<<<dim3(8, Bc / 128), 256, 0, stream>>>(HB, Wt2, b2, HA, 1024, 1024);
    gemm_rq_fused<<<dim3(16, Bc / 128), 256, 0, stream>>>(
        HA, Wt3, b3p, x2, out, ld_out, boff, 1024);
  }
}

// Round 3
// 924.223 us; speedup vs baseline: 1.1096x; 1.0218x over previous
//
#include <hip/hip_runtime.h>

// RationalQuadratic: 4-layer MLP conditioner (bf16 MFMA GEMMs) + RQ spline.
// R11: manual LICM of all K-loop addressing. Evidence: fused kernel at
// VALUBusy 64% vs MfmaUtil 25% (R10) — VALU issues ~2.5x the matrix-pipe
// cycles. The branchy 4-iter staging round-robin recomputed byteoff/row/
// qs-swizzle + 64-bit address chains inside the K-loop (16x2 times),
// defeating LICM (gemm4's simple 2-chunk staging ran at VALUBusy 37%).
// Now: staging src pointers precomputed per thread (advance += 64/kp, h=1
// half via +32 folded into the load's imm offset), LDS dst offsets and all
// fragment ds_read offsets hoisted. Schedule/tiles/swizzle unchanged.

typedef __bf16 bf16_t;
typedef __bf16 bf16x8 __attribute__((ext_vector_type(8)));
typedef float f32x4 __attribute__((ext_vector_type(4)));

#define GLOAD_LDS16(g, l)                                               \
  __builtin_amdgcn_global_load_lds(                                     \
      (const __attribute__((address_space(1))) void*)(g),               \
      (__attribute__((address_space(3))) void*)(l), 16, 0, 0)

// ---------------------------------------------------------------------------
// W (K,N) fp32 row-major -> Wt (Npad,K) bf16 row-major. grid (K/64, Npad/64).
__global__ __launch_bounds__(256) void transpose_w(
    const float* __restrict__ W, bf16_t* __restrict__ Wt,
    int K, int N, int Npad) {
  __shared__ float tile[64][65];
  const int kt = blockIdx.x * 64;
  const int nt = blockIdx.y * 64;
  const int r4 = threadIdx.x >> 6;
  const int c = threadIdx.x & 63;
#pragma unroll
  for (int i = 0; i < 16; i++) {
    int r = i * 4 + r4;
    int gn = nt + c;
    tile[r][c] = (gn < N) ? W[(size_t)(kt + r) * N + gn] : 0.0f;
  }
  __syncthreads();
#pragma unroll
  for (int i = 0; i < 16; i++) {
    int r = i * 4 + r4;
    Wt[(size_t)(nt + r) * K + kt + c] = (bf16_t)tile[c][r];
  }
}

// W3 (1024,1472) -> Wt3p (1536,1024) bf16, cols regrouped per-dim with pad:
// padded col n' = d*24 + p (p<23 real, p==23 zero). grid (16, 24).
__global__ __launch_bounds__(256) void transpose_w3p(
    const float* __restrict__ W3, bf16_t* __restrict__ Wt) {
  __shared__ float tile[64][65];
  const int kt = blockIdx.x * 64;
  const int nt = blockIdx.y * 64;
  const int r4 = threadIdx.x >> 6;
  const int c = threadIdx.x & 63;
  const int np = nt + c;
  const int d = np / 24, p = np % 24;
#pragma unroll
  for (int i = 0; i < 16; i++) {
    int r = i * 4 + r4;
    tile[r][c] = (p < 23) ? W3[(size_t)(kt + r) * 1472 + d * 23 + p] : 0.0f;
  }
  __syncthreads();
#pragma unroll
  for (int i = 0; i < 16; i++) {
    int r = i * 4 + r4;
    Wt[(size_t)(nt + r) * 1024 + kt + c] = (bf16_t)tile[c][r];
  }
}

// b3 -> 24-stride padded copy. grid (6,256).
__global__ __launch_bounds__(256) void prep_b3(const float* __restrict__ b3,
                                               float* __restrict__ b3p) {
  int t = blockIdx.x * 256 + threadIdx.x;
  if (t < 1536) {
    int d = t / 24, p = t % 24;
    b3p[t] = (p < 23) ? b3[d * 23 + p] : 0.0f;
  }
}

// ---------------------------------------------------------------------------
// Also zeroes ld_out for this chunk (fused gemm accumulates into it).
__global__ __launch_bounds__(256) void build_x(
    const float* __restrict__ x1, const float* __restrict__ mask1,
    const float* __restrict__ ctx, bf16_t* __restrict__ X,
    float* __restrict__ ld_out, int boff) {
  int idx = blockIdx.x * 256 + threadIdx.x;
  int bl = idx >> 8;
  int c = idx & 255;
  size_t b = (size_t)(boff + bl);
  float v;
  if (c < 64)       v = x1[b * 64 + c];
  else if (c < 128) v = mask1[b * 64 + (c - 64)];
  else              v = ctx[b * 128 + (c - 128)];
  X[(size_t)bl * 256 + c] = (bf16_t)v;
  if (c == 0) ld_out[b] = 0.0f;
}

// ---------------------------------------------------------------------------
// GEMM body: 128x128 tile, 4 waves 2x2, 4x4 frags of 16x16x32 MFMA.
// Two BK=32 K-tiles per barrier pair (R4). Bank-swizzled LDS layout (R7):
// LDS (row, quad) holds global k-chunk (quad ^ ((row>>1)&3)) — conflicts = 0.
// R11: all addresses hoisted out of the K-loop (only pointer += remains).
template <int RELU>
__device__ __forceinline__ void gemm_body(
    const bf16_t* __restrict__ A, const bf16_t* __restrict__ Bt,
    const float* __restrict__ bias, bf16_t* __restrict__ Cout, int N, int K) {
  __shared__ __align__(16) bf16_t As[2][128 * 32];
  __shared__ __align__(16) bf16_t Bs[2][128 * 32];
  const int tid = threadIdx.x;
  const int w = tid >> 6;
  const int lane = tid & 63;
  const int m0 = blockIdx.y * 128;
  const int n0 = blockIdx.x * 128;
  const int wm = (w & 1) * 64;
  const int wn = (w >> 1) * 64;
  const int lrow = lane & 15;
  const int quad = lane >> 4;

  // Hoisted staging addresses (only k advances in-loop).
  const bf16_t* gA[2];
  const bf16_t* gB[2];
  bf16_t* dA[2];
  bf16_t* dB[2];
#pragma unroll
  for (int c = 0; c < 2; c++) {
    const int chunk = w * 2 + c;
    const int byteoff = (chunk << 10) + lane * 16;
    const int row = byteoff >> 6;
    const int qs = ((byteoff >> 4) & 3) ^ ((row >> 1) & 3);
    gA[c] = A + (size_t)(m0 + row) * K + qs * 8;
    gB[c] = Bt + (size_t)(n0 + row) * K + qs * 8;
    dA[c] = &As[0][0] + chunk * 512;
    dB[c] = &Bs[0][0] + chunk * 512;
  }
  // Hoisted fragment LDS element-offsets.
  int offA[4], offB[4];
#pragma unroll
  for (int i = 0; i < 4; i++) {
    const int rowA = wm + i * 16 + lrow;
    offA[i] = rowA * 32 + (quad ^ ((rowA >> 1) & 3)) * 8;
    const int rowB = wn + i * 16 + lrow;
    offB[i] = rowB * 32 + (quad ^ ((rowB >> 1) & 3)) * 8;
  }

  f32x4 acc[4][4];
#pragma unroll
  for (int i = 0; i < 4; i++)
#pragma unroll
    for (int j = 0; j < 4; j++) acc[i][j] = (f32x4){0.f, 0.f, 0.f, 0.f};

  const int nPair = K >> 6;
  for (int kp = 0; kp < nPair; kp++) {
#pragma unroll
    for (int c = 0; c < 2; c++) {
      GLOAD_LDS16(gA[c], dA[c]);             // h=0
      GLOAD_LDS16(gA[c] + 32, dA[c] + 4096); // h=1 (+32 folds to imm offset)
      GLOAD_LDS16(gB[c], dB[c]);
      GLOAD_LDS16(gB[c] + 32, dB[c] + 4096);
      gA[c] += 64;
      gB[c] += 64;
    }
    __syncthreads();
#pragma unroll
    for (int h = 0; h < 2; h++) {
      bf16x8 af[4], bfr[4];
#pragma unroll
      for (int i = 0; i < 4; i++)
        af[i] = *(const bf16x8*)(&As[0][0] + h * 4096 + offA[i]);
#pragma unroll
      for (int j = 0; j < 4; j++)
        bfr[j] = *(const bf16x8*)(&Bs[0][0] + h * 4096 + offB[j]);
#pragma unroll
      for (int i = 0; i < 4; i++)
#pragma unroll
        for (int j = 0; j < 4; j++)
          acc[i][j] = __builtin_amdgcn_mfma_f32_16x16x32_bf16(
              af[i], bfr[j], acc[i][j], 0, 0, 0);
    }
    __syncthreads();
  }

  // C/D layout (m89/m91): col = lane&15, row = quad*4 + reg.
  float bv[4];
#pragma unroll
  for (int j = 0; j < 4; j++) bv[j] = bias[n0 + wn + j * 16 + lrow];
#pragma unroll
  for (int i = 0; i < 4; i++) {
    int rbase = m0 + wm + i * 16 + quad * 4;
#pragma unroll
    for (int j = 0; j < 4; j++) {
      int col = n0 + wn + j * 16 + lrow;
#pragma unroll
      for (int r = 0; r < 4; r++) {
        float v = acc[i][j][r] + bv[j];
        if (RELU) v = fmaxf(v, 0.0f);
        Cout[(size_t)(rbase + r) * N + col] = (bf16_t)v;
      }
    }
  }
}

__global__ __launch_bounds__(256) void gemm_bt(
    const bf16_t* __restrict__ A, const bf16_t* __restrict__ Bt,
    const float* __restrict__ bias, bf16_t* __restrict__ Cout, int N, int K) {
  gemm_body<1>(A, Bt, bias, Cout, N, K);
}

// ---------------------------------------------------------------------------
// Fused last GEMM + RQ spline. Tile 128 rows x 96 cols (= 4 dims x 24
// padded params). 4 waves, each 64x48 (4x3 frags). bf16 P-tile union keeps
// LDS at 28672B -> 5 blocks/CU. R11: staging slots precomputed per wave
// (slots {w, w+4, w+8} always; {w+12} only for w<2) — the old in-loop
// branchy round-robin was the VALUBusy-64% culprit.
__global__ __launch_bounds__(256) void gemm_rq_fused(
    const bf16_t* __restrict__ A, const bf16_t* __restrict__ Bt,
    const float* __restrict__ b3p, const float* __restrict__ x2,
    float* __restrict__ z_out, float* __restrict__ ld_out,
    int boff, int K) {
  union alignas(16) SM {
    struct { bf16_t As[2][128 * 32]; bf16_t Bs[2][96 * 32]; } s;  // 28672 B
    bf16_t Pt[128 * 104];                                         // 26624 B
  };
  __shared__ SM sm;
  const int tid = threadIdx.x;
  const int w = tid >> 6;
  const int lane = tid & 63;
  const int m0 = blockIdx.y * 128;
  const int n0 = blockIdx.x * 96;
  const int wm = (w & 1) * 64;
  const int wn = (w >> 1) * 48;
  const int lrow = lane & 15;
  const int quad = lane >> 4;

  bf16_t* const smB = &sm.s.As[0][0];

  // Hoisted staging slots. chunk = s*4 + w: s=0,1 -> A chunks 0..7;
  // s=2 -> B chunks 0..3; s=3 -> B chunks 4,5 (w<2 only).
  const bf16_t* gsrc[4];
  int o0[4], o1[4];
#pragma unroll
  for (int s = 0; s < 4; s++) {
    const int chunk = s * 4 + w;
    if (chunk < 8) {
      const int byteoff = (chunk << 10) + lane * 16;
      const int row = byteoff >> 6;
      const int qs = ((byteoff >> 4) & 3) ^ ((row >> 1) & 3);
      gsrc[s] = A + (size_t)(m0 + row) * K + qs * 8;
      o0[s] = chunk * 512;                 // As[0]
      o1[s] = 4096 + chunk * 512;          // As[1]
    } else if (chunk < 14) {
      const int cb = chunk - 8;
      const int byteoff = (cb << 10) + lane * 16;
      const int row = byteoff >> 6;
      const int qs = ((byteoff >> 4) & 3) ^ ((row >> 1) & 3);
      gsrc[s] = Bt + (size_t)(n0 + row) * K + qs * 8;
      o0[s] = 8192 + cb * 512;             // Bs[0]
      o1[s] = 8192 + 3072 + cb * 512;      // Bs[1]
    } else {
      gsrc[s] = A;                          // never dereferenced
      o0[s] = 0;
      o1[s] = 0;
    }
  }
  // Hoisted fragment LDS element-offsets.
  int offA[4], offB3[3];
#pragma unroll
  for (int i = 0; i < 4; i++) {
    const int rowA = wm + i * 16 + lrow;
    offA[i] = rowA * 32 + (quad ^ ((rowA >> 1) & 3)) * 8;
  }
#pragma unroll
  for (int j = 0; j < 3; j++) {
    const int rowB = wn + j * 16 + lrow;
    offB3[j] = rowB * 32 + (quad ^ ((rowB >> 1) & 3)) * 8;
  }

  f32x4 acc[4][3];
#pragma unroll
  for (int i = 0; i < 4; i++)
#pragma unroll
    for (int j = 0; j < 3; j++) acc[i][j] = (f32x4){0.f, 0.f, 0.f, 0.f};

  const int nPair = K >> 6;
  for (int kp = 0; kp < nPair; kp++) {
#pragma unroll
    for (int s = 0; s < 3; s++) {
      GLOAD_LDS16(gsrc[s], smB + o0[s]);
      GLOAD_LDS16(gsrc[s] + 32, smB + o1[s]);
      gsrc[s] += 64;
    }
    if (w < 2) {  // wave-uniform
      GLOAD_LDS16(gsrc[3], smB + o0[3]);
      GLOAD_LDS16(gsrc[3] + 32, smB + o1[3]);
      gsrc[3] += 64;
    }
    __syncthreads();
#pragma unroll
    for (int h = 0; h < 2; h++) {
      bf16x8 af[4], bfr[3];
#pragma unroll
      for (int i = 0; i < 4; i++)
        af[i] = *(const bf16x8*)(smB + h * 4096 + offA[i]);
#pragma unroll
      for (int j = 0; j < 3; j++)
        bfr[j] = *(const bf16x8*)(smB + 8192 + h * 3072 + offB3[j]);
#pragma unroll
      for (int i = 0; i < 4; i++)
#pragma unroll
        for (int j = 0; j < 3; j++)
          acc[i][j] = __builtin_amdgcn_mfma_f32_16x16x32_bf16(
              af[i], bfr[j], acc[i][j], 0, 0, 0);
    }
    __syncthreads();
  }

  // --- P-tile (bf16, +bias) into LDS. Last barrier above guarantees no
  // wave still reads As/Bs. C/D layout: col = lane&15, row = quad*4 + reg.
  float bv[3];
#pragma unroll
  for (int j = 0; j < 3; j++) bv[j] = b3p[n0 + wn + j * 16 + lrow];
#pragma unroll
  for (int i = 0; i < 4; i++) {
    const int rbase = wm + i * 16 + quad * 4;
#pragma unroll
    for (int j = 0; j < 3; j++) {
      const int col = wn + j * 16 + lrow;
#pragma unroll
      for (int r = 0; r < 4; r++)
        sm.Pt[(rbase + r) * 104 + col] = (bf16_t)(acc[i][j][r] + bv[j]);
    }
  }
  __syncthreads();

  // --- spline: thread t handles rows (t>>2) and (t>>2)+64, dim t&3.
  const float SHIFT = 0.54132485f;     // log(e-1)
  const float SHIFT_DX = 5.1944682f;   // log(exp(6.0-0.8)-1)
  const float left = -3.0f;
  const float delta_x = 0.8f + log1pf(expf(SHIFT_DX));
  const float right = left + delta_x;
  const float scale = delta_x;
  const int dloc = tid & 3;
  const int dg = blockIdx.x * 4 + dloc;

#pragma unroll
  for (int rr = 0; rr < 2; rr++) {
    const int row = (tid >> 2) + rr * 64;
    const bf16_t* pr = sm.Pt + row * 104 + dloc * 24;
    const size_t bg = (size_t)(boff + m0 + row);
    const float x = x2[bg * 64 + dg];

    // 3x ds_read_b128 (16B-aligned), then statically-indexed registers.
    bf16x8 v0 = *(const bf16x8*)(pr);
    bf16x8 v1 = *(const bf16x8*)(pr + 8);
    bf16x8 v2 = *(const bf16x8*)(pr + 16);
    float pv[24];
#pragma unroll
    for (int j = 0; j < 8; j++) pv[j] = (float)v0[j];
#pragma unroll
    for (int j = 0; j < 8; j++) pv[8 + j] = (float)v1[j];
#pragma unroll
    for (int j = 0; j < 8; j++) pv[16 + j] = (float)v2[j];

    float mw = pv[0];
#pragma unroll
    for (int j = 1; j < 8; j++) mw = fmaxf(mw, pv[j]);
    float ew[8], swv = 0.f;
#pragma unroll
    for (int j = 0; j < 8; j++) { ew[j] = expf(pv[j] - mw); swv += ew[j]; }
    float invw = 1.0f / swv;
    float cw[9];
    cw[0] = left;
    float cum = 0.f;
#pragma unroll
    for (int j = 0; j < 8; j++) {
      cum += 0.1f + 0.2f * ew[j] * invw;
      cw[j + 1] = left + scale * cum;
    }
    float mh = pv[8];
#pragma unroll
    for (int j = 9; j < 16; j++) mh = fmaxf(mh, pv[j]);
    float eh[8], shv = 0.f;
#pragma unroll
    for (int j = 0; j < 8; j++) { eh[j] = expf(pv[8 + j] - mh); shv += eh[j]; }
    float invh = 1.0f / shv;
    float chh[9];
    chh[0] = left;
    float cumh = 0.f;
#pragma unroll
    for (int j = 0; j < 8; j++) {
      cumh += 0.1f + 0.2f * eh[j] * invh;
      chh[j + 1] = left + scale * cumh;
    }
    float dv[9];
    dv[0] = 1.0f;
    dv[8] = 1.0f;
#pragma unroll
    for (int j = 0; j < 7; j++) {
      float v = pv[16 + j] + SHIFT;
      dv[j + 1] = 0.001f + ((v > 20.f) ? v : log1pf(expf(v)));
    }
    int cnt = 0;
#pragma unroll
    for (int j = 0; j < 8; j++) cnt += (cw[j] <= x) ? 1 : 0;
    cnt += ((cw[8] + 1e-6f) <= x) ? 1 : 0;
    int idx = cnt - 1;
    idx = idx < 0 ? 0 : (idx > 7 ? 7 : idx);
    float x_k = cw[0], x_k1 = cw[1], y_k = chh[0], y_k1 = chh[1];
    float d0v = dv[0], d1v = dv[1];
#pragma unroll
    for (int j = 1; j < 8; j++) {
      bool s = (idx == j);
      x_k = s ? cw[j] : x_k;
      x_k1 = s ? cw[j + 1] : x_k1;
      y_k = s ? chh[j] : y_k;
      y_k1 = s ? chh[j + 1] : y_k1;
      d0v = s ? dv[j] : d0v;
      d1v = s ? dv[j + 1] : d1v;
    }
    float x_kd = x_k1 - x_k;
    float y_kd = y_k1 - y_k;
    float s_k = y_kd / x_kd;
    float xi = (x - x_k) / x_kd;
    float xi1m = xi * (1.f - xi);
    float alpha_k = y_kd * (s_k * xi * xi + d0v * xi1m);
    float beta_k = s_k + (d1v + d0v - 2.f * s_k) * xi1m;
    float z_sp = y_k + alpha_k / fmaxf(beta_k, 1e-8f);
    float oxi = 1.f - xi;
    float num = s_k * s_k * (d1v * xi * xi + 2.f * s_k * xi1m + d0v * oxi * oxi);
    float ld_sp = logf(fmaxf(num, 1e-8f)) - 2.f * logf(fmaxf(beta_k, 1e-8f));

    bool inside = (left <= x) && (x < right);
    z_out[bg * 64 + dg] = inside ? z_sp : x;
    float ldv = inside ? ld_sp : 0.f;
    ldv += __shfl_xor(ldv, 1);
    ldv += __shfl_xor(ldv, 2);
    if (dloc == 0) atomicAdd(&ld_out[bg], ldv);
  }
}

// ---------------------------------------------------------------------------
extern "C" void kernel_launch(void* const* d_in, const int* in_sizes, int n_in,
                              void* d_out, int out_size, void* d_ws,
                              size_t ws_size, hipStream_t stream) {
  const float* x1 = (const float*)d_in[0];
  const float* x2 = (const float*)d_in[1];
  const float* ctx = (const float*)d_in[2];
  const float* mask1 = (const float*)d_in[3];
  const float* W0 = (const float*)d_in[4];
  const float* b0 = (const float*)d_in[5];
  const float* W1 = (const float*)d_in[6];
  const float* b1 = (const float*)d_in[7];
  const float* W2 = (const float*)d_in[8];
  const float* b2 = (const float*)d_in[9];
  const float* W3 = (const float*)d_in[10];
  const float* b3 = (const float*)d_in[11];
  float* out = (float*)d_out;

  const int B = 65536;
  char* ws = (char*)d_ws;

  bf16_t* Wt0 = (bf16_t*)ws;                           // 1024x256  (512 KB)
  bf16_t* Wt1 = (bf16_t*)(ws + 524288);                // 1024x1024 (2 MB)
  bf16_t* Wt2 = (bf16_t*)(ws + 524288 + 2097152);      // 1024x1024 (2 MB)
  bf16_t* Wt3 = (bf16_t*)(ws + 524288 + 2 * 2097152);  // 1536x1024 (3 MB)
  float* b3p = (float*)(ws + 524288 + 2 * 2097152 + 3145728);  // 6 KB
  const size_t wend = 524288 + 2 * 2097152 + 3145728 + 8192;

  // Adaptive chunking, prefer C=1. Per-row: HA 2048 B + aliased region
  // 2048 B (X 512 / HB 2048 — lifetimes disjoint; P eliminated by fusion).
  int C = 4;
  if (wend + (size_t)B * 4096 <= ws_size) C = 1;
  else if (wend + (size_t)(B / 2) * 4096 <= ws_size) C = 2;
  const int Bc = B / C;
  bf16_t* HA = (bf16_t*)(ws + wend);
  char* R = ws + wend + (size_t)Bc * 2048;
  bf16_t* X = (bf16_t*)R;
  bf16_t* HB = (bf16_t*)R;
  float* ld_out = out + (size_t)B * 64;

  transpose_w<<<dim3(4, 16), 256, 0, stream>>>(W0, Wt0, 256, 1024, 1024);
  transpose_w<<<dim3(16, 16), 256, 0, stream>>>(W1, Wt1, 1024, 1024, 1024);
  transpose_w<<<dim3(16, 16), 256, 0, stream>>>(W2, Wt2, 1024, 1024, 1024);
  transpose_w3p<<<dim3(16, 24), 256, 0, stream>>>(W3, Wt3);
  prep_b3<<<6, 256, 0, stream>>>(b3, b3p);

  for (int c = 0; c < C; c++) {
    const int boff = c * Bc;
    build_x<<<Bc, 256, 0, stream>>>(x1, mask1, ctx, X, ld_out, boff);
    gemm_bt<<<dim3(8, Bc / 128), 256, 0, stream>>>(X, Wt0, b0, HA, 1024, 256);
    gemm_bt<<<dim3(8, Bc / 128), 256, 0, stream>>>(HA, Wt1, b1, HB, 1024, 1024);
    gemm_bt<<<dim3(8, Bc / 128), 256, 0, stream>>>(HB, Wt2, b2, HA, 1024, 1024);
    gemm_rq_fused<<<dim3(16, Bc / 128), 256, 0, stream>>>(
        HA, Wt3, b3p, x2, out, ld_out, boff, 1024);
  }
}

// Round 4
// 819.244 us; speedup vs baseline: 1.2517x; 1.1281x over previous
//
#include <hip/hip_runtime.h>

// RationalQuadratic: 4-layer MLP conditioner (bf16 MFMA GEMMs) + RQ spline.
// R12: double N-tile width via 8-wave 512-thread blocks. Evidence: with
// in-loop VALU hoisted (R11), the GEMMs move nTilesN x full-A through the
// L3->LDS staging path (fused: 16 x 134 MB = 2.14 GB in 165 us ~ 13.5 TB/s,
// ~Infinity-Cache BW) while MFMA sits at ~60% and HBM at 25% — staged
// bytes, not latency, is the binder (R10's occupancy bump only bought 7%).
// Mids: 128x256 tiles (grid.x 4), fused: 128x192 (8 dims, grid.x 8).
// Per-wave sub-tiles unchanged (64x64 / 64x48); launch_bounds(512,4) keeps
// regs <=128 -> 2 blocks/CU = 16 waves/CU, same residency as R11.

typedef __bf16 bf16_t;
typedef __bf16 bf16x8 __attribute__((ext_vector_type(8)));
typedef float f32x4 __attribute__((ext_vector_type(4)));

#define GLOAD_LDS16(g, l)                                               \
  __builtin_amdgcn_global_load_lds(                                     \
      (const __attribute__((address_space(1))) void*)(g),               \
      (__attribute__((address_space(3))) void*)(l), 16, 0, 0)

// ---------------------------------------------------------------------------
// W (K,N) fp32 row-major -> Wt (Npad,K) bf16 row-major. grid (K/64, Npad/64).
__global__ __launch_bounds__(256) void transpose_w(
    const float* __restrict__ W, bf16_t* __restrict__ Wt,
    int K, int N, int Npad) {
  __shared__ float tile[64][65];
  const int kt = blockIdx.x * 64;
  const int nt = blockIdx.y * 64;
  const int r4 = threadIdx.x >> 6;
  const int c = threadIdx.x & 63;
#pragma unroll
  for (int i = 0; i < 16; i++) {
    int r = i * 4 + r4;
    int gn = nt + c;
    tile[r][c] = (gn < N) ? W[(size_t)(kt + r) * N + gn] : 0.0f;
  }
  __syncthreads();
#pragma unroll
  for (int i = 0; i < 16; i++) {
    int r = i * 4 + r4;
    Wt[(size_t)(nt + r) * K + kt + c] = (bf16_t)tile[c][r];
  }
}

// W3 (1024,1472) -> Wt3p (1536,1024) bf16, cols regrouped per-dim with pad:
// padded col n' = d*24 + p (p<23 real, p==23 zero). grid (16, 24).
__global__ __launch_bounds__(256) void transpose_w3p(
    const float* __restrict__ W3, bf16_t* __restrict__ Wt) {
  __shared__ float tile[64][65];
  const int kt = blockIdx.x * 64;
  const int nt = blockIdx.y * 64;
  const int r4 = threadIdx.x >> 6;
  const int c = threadIdx.x & 63;
  const int np = nt + c;
  const int d = np / 24, p = np % 24;
#pragma unroll
  for (int i = 0; i < 16; i++) {
    int r = i * 4 + r4;
    tile[r][c] = (p < 23) ? W3[(size_t)(kt + r) * 1472 + d * 23 + p] : 0.0f;
  }
  __syncthreads();
#pragma unroll
  for (int i = 0; i < 16; i++) {
    int r = i * 4 + r4;
    Wt[(size_t)(nt + r) * 1024 + kt + c] = (bf16_t)tile[c][r];
  }
}

// b3 -> 24-stride padded copy. grid (6,256).
__global__ __launch_bounds__(256) void prep_b3(const float* __restrict__ b3,
                                               float* __restrict__ b3p) {
  int t = blockIdx.x * 256 + threadIdx.x;
  if (t < 1536) {
    int d = t / 24, p = t % 24;
    b3p[t] = (p < 23) ? b3[d * 23 + p] : 0.0f;
  }
}

// ---------------------------------------------------------------------------
// Also zeroes ld_out for this chunk (fused gemm accumulates into it).
__global__ __launch_bounds__(256) void build_x(
    const float* __restrict__ x1, const float* __restrict__ mask1,
    const float* __restrict__ ctx, bf16_t* __restrict__ X,
    float* __restrict__ ld_out, int boff) {
  int idx = blockIdx.x * 256 + threadIdx.x;
  int bl = idx >> 8;
  int c = idx & 255;
  size_t b = (size_t)(boff + bl);
  float v;
  if (c < 64)       v = x1[b * 64 + c];
  else if (c < 128) v = mask1[b * 64 + (c - 64)];
  else              v = ctx[b * 128 + (c - 128)];
  X[(size_t)bl * 256 + c] = (bf16_t)v;
  if (c == 0) ld_out[b] = 0.0f;
}

// ---------------------------------------------------------------------------
// Mid GEMM: 128x256 tile, 8 waves (512 thr) in 2x4, each wave 64x64 (4x4
// frags of 16x16x32 MFMA). Two BK=32 K-tiles per barrier pair. Bank-swizzled
// LDS (R7): position-quad q holds global k-chunk q ^ ((row>>1)&3). All
// addressing hoisted (R11). ReLU epilogue.
__global__ __launch_bounds__(512, 4) void gemm_bt(
    const bf16_t* __restrict__ A, const bf16_t* __restrict__ Bt,
    const float* __restrict__ bias, bf16_t* __restrict__ Cout, int N, int K) {
  __shared__ __align__(16) bf16_t As[2][128 * 32];   // 8 KB/half
  __shared__ __align__(16) bf16_t Bs[2][256 * 32];   // 16 KB/half
  const int tid = threadIdx.x;
  const int w = tid >> 6;          // 0..7
  const int lane = tid & 63;
  const int m0 = blockIdx.y * 128;
  const int n0 = blockIdx.x * 256;
  const int wm = (w & 1) * 64;
  const int wn = (w >> 1) * 64;    // 0..192
  const int lrow = lane & 15;
  const int quad = lane >> 4;

  // Staging: A has 8 x 1KB chunks/half -> wave w takes chunk w.
  //          B has 16 chunks/half -> wave w takes chunks w and w+8.
  const bf16_t* gA;
  {
    const int byteoff = (w << 10) + lane * 16;
    const int row = byteoff >> 6;
    const int qs = ((byteoff >> 4) & 3) ^ ((row >> 1) & 3);
    gA = A + (size_t)(m0 + row) * K + qs * 8;
  }
  const bf16_t* gB0;
  const bf16_t* gB1;
  {
    int byteoff = (w << 10) + lane * 16;
    int row = byteoff >> 6;
    int qs = ((byteoff >> 4) & 3) ^ ((row >> 1) & 3);
    gB0 = Bt + (size_t)(n0 + row) * K + qs * 8;
    byteoff = ((w + 8) << 10) + lane * 16;
    row = byteoff >> 6;
    qs = ((byteoff >> 4) & 3) ^ ((row >> 1) & 3);
    gB1 = Bt + (size_t)(n0 + row) * K + qs * 8;
  }
  bf16_t* const dA0 = &As[0][0] + w * 512;          // h=1 at +4096
  bf16_t* const dB0 = &Bs[0][0] + w * 512;          // h=1 at +8192
  bf16_t* const dB1 = &Bs[0][0] + (w + 8) * 512;

  // Hoisted fragment LDS element-offsets.
  int offA[4], offB[4];
#pragma unroll
  for (int i = 0; i < 4; i++) {
    const int rowA = wm + i * 16 + lrow;
    offA[i] = rowA * 32 + (quad ^ ((rowA >> 1) & 3)) * 8;
    const int rowB = wn + i * 16 + lrow;
    offB[i] = rowB * 32 + (quad ^ ((rowB >> 1) & 3)) * 8;
  }

  f32x4 acc[4][4];
#pragma unroll
  for (int i = 0; i < 4; i++)
#pragma unroll
    for (int j = 0; j < 4; j++) acc[i][j] = (f32x4){0.f, 0.f, 0.f, 0.f};

  const int nPair = K >> 6;
  for (int kp = 0; kp < nPair; kp++) {
    GLOAD_LDS16(gA, dA0);
    GLOAD_LDS16(gA + 32, dA0 + 4096);
    GLOAD_LDS16(gB0, dB0);
    GLOAD_LDS16(gB0 + 32, dB0 + 8192);
    GLOAD_LDS16(gB1, dB1);
    GLOAD_LDS16(gB1 + 32, dB1 + 8192);
    gA += 64;
    gB0 += 64;
    gB1 += 64;
    __syncthreads();
#pragma unroll
    for (int h = 0; h < 2; h++) {
      bf16x8 af[4], bfr[4];
#pragma unroll
      for (int i = 0; i < 4; i++)
        af[i] = *(const bf16x8*)(&As[0][0] + h * 4096 + offA[i]);
#pragma unroll
      for (int j = 0; j < 4; j++)
        bfr[j] = *(const bf16x8*)(&Bs[0][0] + h * 8192 + offB[j]);
#pragma unroll
      for (int i = 0; i < 4; i++)
#pragma unroll
        for (int j = 0; j < 4; j++)
          acc[i][j] = __builtin_amdgcn_mfma_f32_16x16x32_bf16(
              af[i], bfr[j], acc[i][j], 0, 0, 0);
    }
    __syncthreads();
  }

  // C/D layout (m89/m91): col = lane&15, row = quad*4 + reg.
  float bv[4];
#pragma unroll
  for (int j = 0; j < 4; j++) bv[j] = bias[n0 + wn + j * 16 + lrow];
#pragma unroll
  for (int i = 0; i < 4; i++) {
    int rbase = m0 + wm + i * 16 + quad * 4;
#pragma unroll
    for (int j = 0; j < 4; j++) {
      int col = n0 + wn + j * 16 + lrow;
#pragma unroll
      for (int r = 0; r < 4; r++) {
        float v = fmaxf(acc[i][j][r] + bv[j], 0.0f);
        Cout[(size_t)(rbase + r) * N + col] = (bf16_t)v;
      }
    }
  }
}

// ---------------------------------------------------------------------------
// Fused last GEMM + RQ spline. Tile 128 rows x 192 cols (= 8 dims x 24
// padded params). 8 waves (512 thr) 2x4, each wave 64x48 (4x3 frags).
// bf16 Pt union (stride 200: 16B-aligned 48B dim-groups; 8-lane dim-groups
// cover all 32 banks disjointly -> conflict-free b128 reads). LDS 51200B
// -> 2 blocks/CU with launch_bounds(512,4).
__global__ __launch_bounds__(512, 4) void gemm_rq_fused(
    const bf16_t* __restrict__ A, const bf16_t* __restrict__ Bt,
    const float* __restrict__ b3p, const float* __restrict__ x2,
    float* __restrict__ z_out, float* __restrict__ ld_out,
    int boff, int K) {
  union alignas(16) SM {
    struct { bf16_t As[2][128 * 32]; bf16_t Bs[2][192 * 32]; } s;  // 40960 B
    bf16_t Pt[128 * 200];                                          // 51200 B
  };
  __shared__ SM sm;
  const int tid = threadIdx.x;
  const int w = tid >> 6;          // 0..7
  const int lane = tid & 63;
  const int m0 = blockIdx.y * 128;
  const int n0 = blockIdx.x * 192;
  const int wm = (w & 1) * 64;
  const int wn = (w >> 1) * 48;    // 0..144
  const int lrow = lane & 15;
  const int quad = lane >> 4;

  bf16_t* const smB = &sm.s.As[0][0];
  // Layout (elems): As[0]@0, As[1]@4096, Bs[0]@8192, Bs[1]@14336.

  // Staging: A 8 chunks/half -> wave w takes chunk w.
  //          B 12 chunks/half -> wave w takes chunk w; w<4 also chunk w+8.
  const bf16_t* gA;
  {
    const int byteoff = (w << 10) + lane * 16;
    const int row = byteoff >> 6;
    const int qs = ((byteoff >> 4) & 3) ^ ((row >> 1) & 3);
    gA = A + (size_t)(m0 + row) * K + qs * 8;
  }
  const bf16_t* gB0;
  const bf16_t* gB1;
  {
    int byteoff = (w << 10) + lane * 16;
    int row = byteoff >> 6;
    int qs = ((byteoff >> 4) & 3) ^ ((row >> 1) & 3);
    gB0 = Bt + (size_t)(n0 + row) * K + qs * 8;
    const int c1 = (w & 3) + 8;              // only used when w < 4
    byteoff = (c1 << 10) + lane * 16;
    row = byteoff >> 6;
    qs = ((byteoff >> 4) & 3) ^ ((row >> 1) & 3);
    gB1 = Bt + (size_t)(n0 + row) * K + qs * 8;
  }
  bf16_t* const dA0 = smB + w * 512;                    // h=1 at +4096
  bf16_t* const dB0 = smB + 8192 + w * 512;             // h=1 at +6144
  bf16_t* const dB1 = smB + 8192 + ((w & 3) + 8) * 512;

  // Hoisted fragment LDS element-offsets.
  int offA[4], offB3[3];
#pragma unroll
  for (int i = 0; i < 4; i++) {
    const int rowA = wm + i * 16 + lrow;
    offA[i] = rowA * 32 + (quad ^ ((rowA >> 1) & 3)) * 8;
  }
#pragma unroll
  for (int j = 0; j < 3; j++) {
    const int rowB = wn + j * 16 + lrow;
    offB3[j] = rowB * 32 + (quad ^ ((rowB >> 1) & 3)) * 8;
  }

  f32x4 acc[4][3];
#pragma unroll
  for (int i = 0; i < 4; i++)
#pragma unroll
    for (int j = 0; j < 3; j++) acc[i][j] = (f32x4){0.f, 0.f, 0.f, 0.f};

  const int nPair = K >> 6;
  for (int kp = 0; kp < nPair; kp++) {
    GLOAD_LDS16(gA, dA0);
    GLOAD_LDS16(gA + 32, dA0 + 4096);
    GLOAD_LDS16(gB0, dB0);
    GLOAD_LDS16(gB0 + 32, dB0 + 6144);
    if (w < 4) {  // wave-uniform
      GLOAD_LDS16(gB1, dB1);
      GLOAD_LDS16(gB1 + 32, dB1 + 6144);
      gB1 += 64;
    }
    gA += 64;
    gB0 += 64;
    __syncthreads();
#pragma unroll
    for (int h = 0; h < 2; h++) {
      bf16x8 af[4], bfr[3];
#pragma unroll
      for (int i = 0; i < 4; i++)
        af[i] = *(const bf16x8*)(smB + h * 4096 + offA[i]);
#pragma unroll
      for (int j = 0; j < 3; j++)
        bfr[j] = *(const bf16x8*)(smB + 8192 + h * 6144 + offB3[j]);
#pragma unroll
      for (int i = 0; i < 4; i++)
#pragma unroll
        for (int j = 0; j < 3; j++)
          acc[i][j] = __builtin_amdgcn_mfma_f32_16x16x32_bf16(
              af[i], bfr[j], acc[i][j], 0, 0, 0);
    }
    __syncthreads();
  }

  // --- P-tile (bf16, +bias) into LDS. Last barrier above guarantees no
  // wave still reads As/Bs. C/D layout: col = lane&15, row = quad*4 + reg.
  float bv[3];
#pragma unroll
  for (int j = 0; j < 3; j++) bv[j] = b3p[n0 + wn + j * 16 + lrow];
#pragma unroll
  for (int i = 0; i < 4; i++) {
    const int rbase = wm + i * 16 + quad * 4;
#pragma unroll
    for (int j = 0; j < 3; j++) {
      const int col = wn + j * 16 + lrow;
#pragma unroll
      for (int r = 0; r < 4; r++)
        sm.Pt[(rbase + r) * 200 + col] = (bf16_t)(acc[i][j][r] + bv[j]);
    }
  }
  __syncthreads();

  // --- spline: thread t handles rows (t>>3) and (t>>3)+64, dim t&7.
  const float SHIFT = 0.54132485f;     // log(e-1)
  const float SHIFT_DX = 5.1944682f;   // log(exp(6.0-0.8)-1)
  const float left = -3.0f;
  const float delta_x = 0.8f + log1pf(expf(SHIFT_DX));
  const float right = left + delta_x;
  const float scale = delta_x;
  const int dloc = tid & 7;
  const int dg = blockIdx.x * 8 + dloc;

#pragma unroll
  for (int rr = 0; rr < 2; rr++) {
    const int row = (tid >> 3) + rr * 64;
    const bf16_t* pr = sm.Pt + row * 200 + dloc * 24;
    const size_t bg = (size_t)(boff + m0 + row);
    const float x = x2[bg * 64 + dg];

    // 3x ds_read_b128 (byte base = row*400 + dloc*48, 16B-aligned), then
    // statically-indexed registers (rule #20).
    bf16x8 v0 = *(const bf16x8*)(pr);
    bf16x8 v1 = *(const bf16x8*)(pr + 8);
    bf16x8 v2 = *(const bf16x8*)(pr + 16);
    float pv[24];
#pragma unroll
    for (int j = 0; j < 8; j++) pv[j] = (float)v0[j];
#pragma unroll
    for (int j = 0; j < 8; j++) pv[8 + j] = (float)v1[j];
#pragma unroll
    for (int j = 0; j < 8; j++) pv[16 + j] = (float)v2[j];

    float mw = pv[0];
#pragma unroll
    for (int j = 1; j < 8; j++) mw = fmaxf(mw, pv[j]);
    float ew[8], swv = 0.f;
#pragma unroll
    for (int j = 0; j < 8; j++) { ew[j] = expf(pv[j] - mw); swv += ew[j]; }
    float invw = 1.0f / swv;
    float cw[9];
    cw[0] = left;
    float cum = 0.f;
#pragma unroll
    for (int j = 0; j < 8; j++) {
      cum += 0.1f + 0.2f * ew[j] * invw;
      cw[j + 1] = left + scale * cum;
    }
    float mh = pv[8];
#pragma unroll
    for (int j = 9; j < 16; j++) mh = fmaxf(mh, pv[j]);
    float eh[8], shv = 0.f;
#pragma unroll
    for (int j = 0; j < 8; j++) { eh[j] = expf(pv[8 + j] - mh); shv += eh[j]; }
    float invh = 1.0f / shv;
    float chh[9];
    chh[0] = left;
    float cumh = 0.f;
#pragma unroll
    for (int j = 0; j < 8; j++) {
      cumh += 0.1f + 0.2f * eh[j] * invh;
      chh[j + 1] = left + scale * cumh;
    }
    float dv[9];
    dv[0] = 1.0f;
    dv[8] = 1.0f;
#pragma unroll
    for (int j = 0; j < 7; j++) {
      float v = pv[16 + j] + SHIFT;
      dv[j + 1] = 0.001f + ((v > 20.f) ? v : log1pf(expf(v)));
    }
    int cnt = 0;
#pragma unroll
    for (int j = 0; j < 8; j++) cnt += (cw[j] <= x) ? 1 : 0;
    cnt += ((cw[8] + 1e-6f) <= x) ? 1 : 0;
    int idx = cnt - 1;
    idx = idx < 0 ? 0 : (idx > 7 ? 7 : idx);
    float x_k = cw[0], x_k1 = cw[1], y_k = chh[0], y_k1 = chh[1];
    float d0v = dv[0], d1v = dv[1];
#pragma unroll
    for (int j = 1; j < 8; j++) {
      bool s = (idx == j);
      x_k = s ? cw[j] : x_k;
      x_k1 = s ? cw[j + 1] : x_k1;
      y_k = s ? chh[j] : y_k;
      y_k1 = s ? chh[j + 1] : y_k1;
      d0v = s ? dv[j] : d0v;
      d1v = s ? dv[j + 1] : d1v;
    }
    float x_kd = x_k1 - x_k;
    float y_kd = y_k1 - y_k;
    float s_k = y_kd / x_kd;
    float xi = (x - x_k) / x_kd;
    float xi1m = xi * (1.f - xi);
    float alpha_k = y_kd * (s_k * xi * xi + d0v * xi1m);
    float beta_k = s_k + (d1v + d0v - 2.f * s_k) * xi1m;
    float z_sp = y_k + alpha_k / fmaxf(beta_k, 1e-8f);
    float oxi = 1.f - xi;
    float num = s_k * s_k * (d1v * xi * xi + 2.f * s_k * xi1m + d0v * oxi * oxi);
    float ld_sp = logf(fmaxf(num, 1e-8f)) - 2.f * logf(fmaxf(beta_k, 1e-8f));

    bool inside = (left <= x) && (x < right);
    z_out[bg * 64 + dg] = inside ? z_sp : x;
    float ldv = inside ? ld_sp : 0.f;
    ldv += __shfl_xor(ldv, 1);
    ldv += __shfl_xor(ldv, 2);
    ldv += __shfl_xor(ldv, 4);
    if (dloc == 0) atomicAdd(&ld_out[bg], ldv);
  }
}

// ---------------------------------------------------------------------------
extern "C" void kernel_launch(void* const* d_in, const int* in_sizes, int n_in,
                              void* d_out, int out_size, void* d_ws,
                              size_t ws_size, hipStream_t stream) {
  const float* x1 = (const float*)d_in[0];
  const float* x2 = (const float*)d_in[1];
  const float* ctx = (const float*)d_in[2];
  const float* mask1 = (const float*)d_in[3];
  const float* W0 = (const float*)d_in[4];
  const float* b0 = (const float*)d_in[5];
  const float* W1 = (const float*)d_in[6];
  const float* b1 = (const float*)d_in[7];
  const float* W2 = (const float*)d_in[8];
  const float* b2 = (const float*)d_in[9];
  const float* W3 = (const float*)d_in[10];
  const float* b3 = (const float*)d_in[11];
  float* out = (float*)d_out;

  const int B = 65536;
  char* ws = (char*)d_ws;

  bf16_t* Wt0 = (bf16_t*)ws;                           // 1024x256  (512 KB)
  bf16_t* Wt1 = (bf16_t*)(ws + 524288);                // 1024x1024 (2 MB)
  bf16_t* Wt2 = (bf16_t*)(ws + 524288 + 2097152);      // 1024x1024 (2 MB)
  bf16_t* Wt3 = (bf16_t*)(ws + 524288 + 2 * 2097152);  // 1536x1024 (3 MB)
  float* b3p = (float*)(ws + 524288 + 2 * 2097152 + 3145728);  // 6 KB
  const size_t wend = 524288 + 2 * 2097152 + 3145728 + 8192;

  // Adaptive chunking, prefer C=1. Per-row: HA 2048 B + aliased region
  // 2048 B (X 512 / HB 2048 — lifetimes disjoint; P eliminated by fusion).
  int C = 4;
  if (wend + (size_t)B * 4096 <= ws_size) C = 1;
  else if (wend + (size_t)(B / 2) * 4096 <= ws_size) C = 2;
  const int Bc = B / C;
  bf16_t* HA = (bf16_t*)(ws + wend);
  char* R = ws + wend + (size_t)Bc * 2048;
  bf16_t* X = (bf16_t*)R;
  bf16_t* HB = (bf16_t*)R;
  float* ld_out = out + (size_t)B * 64;

  transpose_w<<<dim3(4, 16), 256, 0, stream>>>(W0, Wt0, 256, 1024, 1024);
  transpose_w<<<dim3(16, 16), 256, 0, stream>>>(W1, Wt1, 1024, 1024, 1024);
  transpose_w<<<dim3(16, 16), 256, 0, stream>>>(W2, Wt2, 1024, 1024, 1024);
  transpose_w3p<<<dim3(16, 24), 256, 0, stream>>>(W3, Wt3);
  prep_b3<<<6, 256, 0, stream>>>(b3, b3p);

  for (int c = 0; c < C; c++) {
    const int boff = c * Bc;
    build_x<<<Bc, 256, 0, stream>>>(x1, mask1, ctx, X, ld_out, boff);
    gemm_bt<<<dim3(4, Bc / 128), 512, 0, stream>>>(X, Wt0, b0, HA, 1024, 256);
    gemm_bt<<<dim3(4, Bc / 128), 512, 0, stream>>>(HA, Wt1, b1, HB, 1024, 1024);
    gemm_bt<<<dim3(4, Bc / 128), 512, 0, stream>>>(HB, Wt2, b2, HA, 1024, 1024);
    gemm_rq_fused<<<dim3(8, Bc / 128), 512, 0, stream>>>(
        HA, Wt3, b3p, x2, out, ld_out, boff, 1024);
  }
}